// Round 5
// baseline (195.144 us; speedup 1.0000x reference)
//
#include <hip/hip_runtime.h>
#include <hip/hip_bf16.h>
#include <math.h>

#define NN 2048      // nodes
#define NE 4096      // edges
#define D 128
#define NODE_K 1024
#define EDGE_K 2048
#define CAP 64       // per-node incident-edge list capacity (mean degree 4)
#define ROWS 16

typedef const __hip_bfloat16* bfp;
__device__ __forceinline__ float b2f(__hip_bfloat16 x) { return __bfloat162float(x); }

// prefix offsets (element counts) of the 14 float tensors in the fp32 region
__device__ __constant__ const int kPrefix[15] = {
  0, 262144, 786432, 786560, 786688, 803072, 819456, 835840,
  852224, 868608, 884992, 901376, 901504, 903552, 903568};
#define TOTAL_F 903568

struct CvtSrc { const void* p[14]; };

// ---------- convert: per-block dtype detect + convert all + zero deg ----------
__global__ __launch_bounds__(256) void convert_kernel(
    CvtSrc srcs, float* __restrict__ dst, int* __restrict__ flag, int* __restrict__ deg) {
  int t = threadIdx.x;
  // redundant per-block detection (8 KB read) avoids a separate launch
  const unsigned short* raw = (const unsigned short*)srcs.p[0];
  int weird = 0;
  for (int i = t; i < 4096; i += 256) {
    unsigned int bits = ((unsigned int)raw[i]) << 16;
    float x = __uint_as_float(bits);
    float ax = fabsf(x);
    if (!(ax <= 1e3f) || (x != 0.f && ax < 1e-12f)) weird++;  // nan/inf/huge/denorm
  }
  #pragma unroll
  for (int m = 32; m >= 1; m >>= 1) weird += __shfl_xor(weird, m);
  __shared__ int s[4];
  if ((t & 63) == 0) s[t >> 6] = weird;
  __syncthreads();
  int f = (s[0] + s[1] + s[2] + s[3] > 200) ? 1 : 0;  // 1 => inputs are fp32
  if (blockIdx.x == 0) {
    if (t == 0) flag[0] = f;
    for (int i = t; i < NN; i += 256) deg[i] = 0;
  }
  for (int i = blockIdx.x * 256 + t; i < TOTAL_F; i += gridDim.x * 256) {
    int tt = 0;
    while (i >= kPrefix[tt + 1]) ++tt;
    int off = i - kPrefix[tt];
    dst[i] = f ? ((const float*)srcs.p[tt])[off] : b2f(((bfp)srcs.p[tt])[off]);
  }
}

// ---------- scores (fp64 acc, rank stability) + build incident lists ----------
#define SCORE_BLOCKS ((NN + NE) / 4)
__global__ __launch_bounds__(256) void scores_lists_kernel(
    const float* __restrict__ nf, const float* __restrict__ ef,
    const float* __restrict__ wrn, const float* __restrict__ wre,
    float* __restrict__ ns, float* __restrict__ es,
    const int* __restrict__ src, const int* __restrict__ dst,
    int* __restrict__ deg, int* __restrict__ lists) {
  int b = blockIdx.x, t = threadIdx.x;
  if (b < SCORE_BLOCKS) {
    int wid = b * 4 + (t >> 6), lane = t & 63;
    const float* row; const float* w; float* out;
    if (wid < NN) { row = nf + (size_t)wid * D;        w = wrn; out = ns + wid; }
    else          { int r = wid - NN; row = ef + (size_t)r * D; w = wre; out = es + r; }
    double p = (double)row[lane] * (double)w[lane]
             + (double)row[lane + 64] * (double)w[lane + 64];
    #pragma unroll
    for (int m = 32; m >= 1; m >>= 1) p += __shfl_xor(p, m);
    if (lane == 0) *out = (float)p;
  } else {
    int e = (b - SCORE_BLOCKS) * 256 + t;
    if (e < NE) {
      int s = src[e], d = dst[e];
      int p = atomicAdd(&deg[s], 1);
      if (p >= 0 && p < CAP) lists[s * CAP + p] = e;
      if (d != s) {
        p = atomicAdd(&deg[d], 1);
        if (p >= 0 && p < CAP) lists[d * CAP + p] = e;
      }
    }
  }
}

// ---------- exact top-k via stable rank, wave-parallel ----------
__global__ __launch_bounds__(256) void node_mask_kernel(
    const float* __restrict__ ns, int* __restrict__ node_mask) {
  __shared__ float s[NN];
  int t = threadIdx.x;
  for (int i = t; i < NN; i += 256) s[i] = ns[i];
  __syncthreads();
  int i = blockIdx.x * 4 + (t >> 6), lane = t & 63;
  float si = s[i];
  int rank = 0;
  for (int j = lane; j < NN; j += 64) {
    float sj = s[j];
    rank += (sj > si) || (sj == si && j < i);
  }
  #pragma unroll
  for (int m = 32; m >= 1; m >>= 1) rank += __shfl_xor(rank, m);
  if (lane == 0) node_mask[i] = (rank < NODE_K) ? 1 : 0;
}

__global__ __launch_bounds__(256) void edge_mask_kernel(
    const float* __restrict__ es, const int* __restrict__ src,
    const int* __restrict__ dst, const int* __restrict__ node_mask,
    int* __restrict__ edge_mask) {
  __shared__ float s[NE];
  int t = threadIdx.x;
  for (int i = t; i < NE; i += 256) s[i] = es[i];
  __syncthreads();
  int i = blockIdx.x * 4 + (t >> 6), lane = t & 63;
  float si = s[i];
  int rank = 0;
  for (int j = lane; j < NE; j += 64) {
    float sj = s[j];
    rank += (sj > si) || (sj == si && j < i);
  }
  #pragma unroll
  for (int m = 32; m >= 1; m >>= 1) rank += __shfl_xor(rank, m);
  if (lane == 0)
    edge_mask[i] = ((rank < EDGE_K) && node_mask[src[i]] && node_mask[dst[i]]) ? 1 : 0;
}

// ---------- shared GEMM pass: acc[8] += As(16x128 LDS) @ Wg(128x128 global) ------
// A reads: wave-uniform float4 broadcasts (k blocked by 4). 12 LDS instr / 32 FMA.
__device__ __forceinline__ void gemm_pass(const float* __restrict__ Wg,
                                          float* __restrict__ Wl,
                                          const float* __restrict__ As,
                                          int j, int rg, float acc[8]) {
  for (int half = 0; half < 2; ++half) {
    __syncthreads();
    for (int i = threadIdx.x; i < 64 * D; i += 256) Wl[i] = Wg[half * 64 * D + i];
    __syncthreads();
    #pragma unroll 4
    for (int k4 = 0; k4 < 16; ++k4) {
      int kr = k4 * 4;                 // row in Wl
      int k0 = half * 64 + kr;         // col in As
      float w0 = Wl[(kr + 0) * D + j];
      float w1 = Wl[(kr + 1) * D + j];
      float w2 = Wl[(kr + 2) * D + j];
      float w3 = Wl[(kr + 3) * D + j];
      #pragma unroll
      for (int r = 0; r < 8; ++r) {
        float4 a = ((const float4*)As)[((rg * 8 + r) * D + k0) >> 2];
        acc[r] += a.x * w0 + a.y * w1 + a.z * w2 + a.w * w3;
      }
    }
  }
}

// ---------- fused: gather(efm,nsum) -> h -> q,k,v (5 GEMM passes, 1 launch) ------
__global__ __launch_bounds__(256) void h_qkv_kernel(
    const float* __restrict__ EF, const float* __restrict__ NF,
    const int* __restrict__ src, const int* __restrict__ dst,
    const int* __restrict__ edge_mask,
    const float* __restrict__ WE, const float* __restrict__ WN,
    const float* __restrict__ WQ0,  // WQ,WK,WV contiguous
    float* __restrict__ qkv) {
  __shared__ __align__(16) float Wl[64 * D];   // 32 KB
  __shared__ __align__(16) float A1[ROWS * D]; // efm, reused as Hl
  __shared__ __align__(16) float A2[ROWS * D]; // nsum
  int t = threadIdx.x;
  int row0 = blockIdx.x * ROWS;
  for (int i = t; i < ROWS * D; i += 256) {
    int e = row0 + (i >> 7), c = i & 127;
    float m = edge_mask[e] ? 1.f : 0.f;
    A1[i] = m * EF[(size_t)e * D + c];
    A2[i] = NF[(size_t)src[e] * D + c] + NF[(size_t)dst[e] * D + c];
  }
  int j = t & 127, rg = t >> 7;
  float acc[8] = {0, 0, 0, 0, 0, 0, 0, 0};
  gemm_pass(WE, Wl, A1, j, rg, acc);   // h += efm @ w_e
  gemm_pass(WN, Wl, A2, j, rg, acc);   // h += nsum @ w_n
  __syncthreads();                     // all reads of A1 done (part0 finished earlier)
  #pragma unroll
  for (int r = 0; r < 8; ++r) A1[(rg * 8 + r) * D + j] = acc[r];  // Hl := h
  // q,k,v passes (gemm_pass begins with __syncthreads -> Hl visible)
  for (int sel = 0; sel < 3; ++sel) {
    float a2[8] = {0, 0, 0, 0, 0, 0, 0, 0};
    gemm_pass(WQ0 + (size_t)sel * D * D, Wl, A1, j, rg, a2);
    float* C = qkv + (size_t)sel * NE * D;
    #pragma unroll
    for (int r = 0; r < 8; ++r) C[(size_t)(row0 + rg * 8 + r) * D + j] = a2[r];
  }
}

// ---------- sparse edge attention: one block (128 thr) per query edge ----------
__global__ void attn_kernel(const float* __restrict__ q, const float* __restrict__ k,
                            const float* __restrict__ v, const int* __restrict__ src,
                            const int* __restrict__ dst, const int* __restrict__ deg,
                            const int* __restrict__ lists, float* __restrict__ ao) {
  int e = blockIdx.x;
  int j = threadIdx.x;  // head = j/32, d = j%32 (shfl_xor<32 stays in-head)
  float qj = q[e * D + j];
  int sn = src[e], dn = dst[e];
  float m = -1e30f, l = 0.f, acc = 0.f;
  const float scale = 0.17677669529663687f;  // 1/sqrt(32)
  int degA = max(0, min(deg[sn], CAP));
  for (int i = 0; i < degA; ++i) {
    int f = lists[sn * CAP + i];
    float p = qj * k[f * D + j];
    p += __shfl_xor(p, 16); p += __shfl_xor(p, 8); p += __shfl_xor(p, 4);
    p += __shfl_xor(p, 2);  p += __shfl_xor(p, 1);
    float s = p * scale;
    float vj = v[f * D + j];
    float mn = fmaxf(m, s);
    float corr = expf(m - mn);
    float w = expf(s - mn);
    l = l * corr + w;
    acc = acc * corr + w * vj;
    m = mn;
  }
  if (dn != sn) {
    int degB = max(0, min(deg[dn], CAP));
    for (int i = 0; i < degB; ++i) {
      int f = lists[dn * CAP + i];
      if (src[f] == sn || dst[f] == sn) continue;  // already in list A
      float p = qj * k[f * D + j];
      p += __shfl_xor(p, 16); p += __shfl_xor(p, 8); p += __shfl_xor(p, 4);
      p += __shfl_xor(p, 2);  p += __shfl_xor(p, 1);
      float s = p * scale;
      float vj = v[f * D + j];
      float mn = fmaxf(m, s);
      float corr = expf(m - mn);
      float w = expf(s - mn);
      l = l * corr + w;
      acc = acc * corr + w * vj;
      m = mn;
    }
  }
  ao[e * D + j] = acc / fmaxf(l, 1e-37f);
}

// ---------- fused epilogue: o = ao@WO; x = gelu(o@W1+b1); logits = x@W2+b2 -------
__global__ __launch_bounds__(256) void o_mlp_logits_kernel(
    const float* __restrict__ ao, const float* __restrict__ WO,
    const float* __restrict__ W1, const float* __restrict__ B1,
    const float* __restrict__ W2, const float* __restrict__ B2,
    const int* __restrict__ flag, void* __restrict__ out) {
  __shared__ __align__(16) float Wl[64 * D];   // 32 KB
  __shared__ __align__(16) float Al[ROWS * D]; // ao rows, reused as x
  __shared__ __align__(16) float Bl[ROWS * D]; // o rows
  int t = threadIdx.x;
  int row0 = blockIdx.x * ROWS;
  for (int i = t; i < ROWS * D; i += 256) Al[i] = ao[(size_t)row0 * D + i];
  int j = t & 127, rg = t >> 7;
  // o = ao @ w_o
  float acc[8] = {0, 0, 0, 0, 0, 0, 0, 0};
  gemm_pass(WO, Wl, Al, j, rg, acc);
  __syncthreads();
  #pragma unroll
  for (int r = 0; r < 8; ++r) Bl[(rg * 8 + r) * D + j] = acc[r];
  // x = gelu(o @ w1 + b1)
  float acc2[8] = {0, 0, 0, 0, 0, 0, 0, 0};
  gemm_pass(W1, Wl, Bl, j, rg, acc2);   // leading sync makes Bl visible
  float bj = B1[j];
  __syncthreads();                      // all reads of Al done before overwrite
  #pragma unroll
  for (int r = 0; r < 8; ++r) {
    float u = acc2[r] + bj;
    float inner = 0.7978845608028654f * (u + 0.044715f * u * u * u);
    Al[(rg * 8 + r) * D + j] = 0.5f * u * (1.f + tanhf(inner));
  }
  __syncthreads();
  // logits = x @ w2 + b2  (w2 is 128x16 = 2048 floats)
  for (int i = t; i < D * 16; i += 256) Wl[i] = W2[i];
  __syncthreads();
  int r = t >> 4, c = t & 15;
  float s = 0.f;
  for (int kk = 0; kk < D; ++kk) s += Al[r * D + kk] * Wl[kk * 16 + c];
  s += B2[c];
  int idx = (row0 + r) * 16 + c;
  if (flag[0]) ((float*)out)[idx] = s;
  else ((__hip_bfloat16*)out)[idx] = __float2bfloat16(s);
}

extern "C" void kernel_launch(void* const* d_in, const int* in_sizes, int n_in,
                              void* d_out, int out_size, void* d_ws, size_t ws_size,
                              hipStream_t stream) {
  const int* eidx = (const int*)d_in[2];
  const int* src = eidx;
  const int* dst = eidx + NE;

  size_t off = 0;
  char* base = (char*)d_ws;
  auto alloc = [&](size_t nbytes) -> void* {
    void* p = base + off;
    off += (nbytes + 255) & ~(size_t)255;
    return p;
  };
  int* flag        = (int*)alloc(256);
  float* F         = (float*)alloc((size_t)TOTAL_F * sizeof(float));
  float* ns        = (float*)alloc(NN * sizeof(float));
  float* es        = (float*)alloc(NE * sizeof(float));
  int* node_mask   = (int*)alloc(NN * sizeof(int));
  int* edge_mask   = (int*)alloc(NE * sizeof(int));
  int* deg         = (int*)alloc(NN * sizeof(int));
  int* lists       = (int*)alloc((size_t)NN * CAP * sizeof(int));
  float* qkv       = (float*)alloc((size_t)3 * NE * D * sizeof(float));
  float* ao        = (float*)alloc((size_t)NE * D * sizeof(float));
  float* qb = qkv, *kb = qkv + NE * D, *vb = qkv + 2 * NE * D;

  const float* NF  = F + 0;
  const float* EF  = F + 262144;
  const float* WRN = F + 786432;
  const float* WRE = F + 786560;
  const float* WE  = F + 786688;
  const float* WNp = F + 803072;
  const float* WQ  = F + 819456;   // WQ,WK,WV contiguous
  const float* WO  = F + 868608;
  const float* W1  = F + 884992;
  const float* B1  = F + 901376;
  const float* W2P = F + 901504;
  const float* B2P = F + 903552;

  CvtSrc srcs;
  srcs.p[0]  = d_in[0];  srcs.p[1]  = d_in[1];  srcs.p[2]  = d_in[3];
  srcs.p[3]  = d_in[4];  srcs.p[4]  = d_in[5];  srcs.p[5]  = d_in[6];
  srcs.p[6]  = d_in[7];  srcs.p[7]  = d_in[8];  srcs.p[8]  = d_in[9];
  srcs.p[9]  = d_in[10]; srcs.p[10] = d_in[11]; srcs.p[11] = d_in[12];
  srcs.p[12] = d_in[13]; srcs.p[13] = d_in[14];

  convert_kernel<<<512, 256, 0, stream>>>(srcs, F, flag, deg);
  scores_lists_kernel<<<SCORE_BLOCKS + NE / 256, 256, 0, stream>>>(
      NF, EF, WRN, WRE, ns, es, src, dst, deg, lists);
  node_mask_kernel<<<NN / 4, 256, 0, stream>>>(ns, node_mask);
  edge_mask_kernel<<<NE / 4, 256, 0, stream>>>(es, src, dst, node_mask, edge_mask);
  h_qkv_kernel<<<NE / ROWS, 256, 0, stream>>>(EF, NF, src, dst, edge_mask,
                                              WE, WNp, WQ, qkv);
  attn_kernel<<<NE, 128, 0, stream>>>(qb, kb, vb, src, dst, deg, lists, ao);
  o_mlp_logits_kernel<<<NE / ROWS, 256, 0, stream>>>(ao, WO, W1, B1, W2P, B2P,
                                                     flag, d_out);
}

// Round 6
// 174.260 us; speedup vs baseline: 1.1198x; 1.1198x over previous
//
#include <hip/hip_runtime.h>
#include <hip/hip_bf16.h>
#include <math.h>

#define NN 2048      // nodes
#define NE 4096      // edges
#define D 128
#define NODE_K 1024
#define EDGE_K 2048
#define CAP 64       // per-node incident-edge list capacity (mean degree 4)
#define ROWS 16
#define BT 512       // threads for fused GEMM kernels (8 waves -> 2/SIMD)

typedef const __hip_bfloat16* bfp;
__device__ __forceinline__ float b2f(__hip_bfloat16 x) { return __bfloat162float(x); }

// dual-path loads: f=1 -> fp32 input, f=0 -> bf16 input
__device__ __forceinline__ float ldx(const void* p, size_t i, int f) {
  return f ? ((const float*)p)[i] : b2f(((bfp)p)[i]);
}
__device__ __forceinline__ float4 ldx4(const void* p, size_t i4, int f) {
  if (f) return ((const float4*)p)[i4];
  ushort4 u = ((const ushort4*)p)[i4];
  float4 r;
  r.x = b2f(*(const __hip_bfloat16*)&u.x);
  r.y = b2f(*(const __hip_bfloat16*)&u.y);
  r.z = b2f(*(const __hip_bfloat16*)&u.z);
  r.w = b2f(*(const __hip_bfloat16*)&u.w);
  return r;
}

// prefix offsets of the 12 WEIGHT tensors in the converted fp32 region
// (node/edge features stay in their raw buffers, read dual-path)
__device__ __constant__ const int kPrefix[13] = {
  0, 128, 256, 16640, 33024, 49408, 65792, 82176, 98560, 114944, 115072,
  117120, 117136};
#define TOTAL_W 117136

struct CvtSrc { const void* p[12]; };

// ---------- convert weights + dtype detect + zero deg ----------
__global__ __launch_bounds__(256) void convert_kernel(
    const unsigned short* __restrict__ nf_raw, CvtSrc srcs,
    float* __restrict__ dst, int* __restrict__ flag, int* __restrict__ deg) {
  int t = threadIdx.x;
  int weird = 0;
  for (int i = t; i < 4096; i += 256) {
    unsigned int bits = ((unsigned int)nf_raw[i]) << 16;
    float x = __uint_as_float(bits);
    float ax = fabsf(x);
    if (!(ax <= 1e3f) || (x != 0.f && ax < 1e-12f)) weird++;  // nan/inf/huge/denorm
  }
  #pragma unroll
  for (int m = 32; m >= 1; m >>= 1) weird += __shfl_xor(weird, m);
  __shared__ int s[4];
  if ((t & 63) == 0) s[t >> 6] = weird;
  __syncthreads();
  int f = (s[0] + s[1] + s[2] + s[3] > 200) ? 1 : 0;  // 1 => inputs are fp32
  if (blockIdx.x == 0) {
    if (t == 0) flag[0] = f;
    for (int i = t; i < NN; i += 256) deg[i] = 0;
  }
  for (int i = blockIdx.x * 256 + t; i < TOTAL_W; i += gridDim.x * 256) {
    int tt = 0;
    while (i >= kPrefix[tt + 1]) ++tt;
    dst[i] = ldx(srcs.p[tt], i - kPrefix[tt], f);
  }
}

// ---------- scores (fp64 acc, rank stability) + build incident lists ----------
#define SCORE_BLOCKS ((NN + NE) / 4)
__global__ __launch_bounds__(256) void scores_lists_kernel(
    const void* __restrict__ rawNF, const void* __restrict__ rawEF,
    const float* __restrict__ wrn, const float* __restrict__ wre,
    const int* __restrict__ flag,
    float* __restrict__ ns, float* __restrict__ es,
    const int* __restrict__ src, const int* __restrict__ dst,
    int* __restrict__ deg, int* __restrict__ lists) {
  int b = blockIdx.x, t = threadIdx.x;
  if (b < SCORE_BLOCKS) {
    int f = flag[0];
    int wid = b * 4 + (t >> 6), lane = t & 63;
    const void* base; const float* w; float* out; size_t r0;
    if (wid < NN) { base = rawNF; r0 = (size_t)wid * D;        w = wrn; out = ns + wid; }
    else { int r = wid - NN; base = rawEF; r0 = (size_t)r * D; w = wre; out = es + r; }
    double p = (double)ldx(base, r0 + lane, f) * (double)w[lane]
             + (double)ldx(base, r0 + lane + 64, f) * (double)w[lane + 64];
    #pragma unroll
    for (int m = 32; m >= 1; m >>= 1) p += __shfl_xor(p, m);
    if (lane == 0) *out = (float)p;
  } else {
    int e = (b - SCORE_BLOCKS) * 256 + t;
    if (e < NE) {
      int s = src[e], d = dst[e];
      int p = atomicAdd(&deg[s], 1);
      if (p >= 0 && p < CAP) lists[s * CAP + p] = e;
      if (d != s) {
        p = atomicAdd(&deg[d], 1);
        if (p >= 0 && p < CAP) lists[d * CAP + p] = e;
      }
    }
  }
}

// ---------- exact top-k via stable rank, wave-parallel ----------
__global__ __launch_bounds__(256) void node_mask_kernel(
    const float* __restrict__ ns, int* __restrict__ node_mask) {
  __shared__ float s[NN];
  int t = threadIdx.x;
  for (int i = t; i < NN; i += 256) s[i] = ns[i];
  __syncthreads();
  int i = blockIdx.x * 4 + (t >> 6), lane = t & 63;
  float si = s[i];
  int rank = 0;
  for (int j = lane; j < NN; j += 64) {
    float sj = s[j];
    rank += (sj > si) || (sj == si && j < i);
  }
  #pragma unroll
  for (int m = 32; m >= 1; m >>= 1) rank += __shfl_xor(rank, m);
  if (lane == 0) node_mask[i] = (rank < NODE_K) ? 1 : 0;
}

__global__ __launch_bounds__(256) void edge_mask_kernel(
    const float* __restrict__ es, const int* __restrict__ src,
    const int* __restrict__ dst, const int* __restrict__ node_mask,
    int* __restrict__ edge_mask) {
  __shared__ float s[NE];
  int t = threadIdx.x;
  for (int i = t; i < NE; i += 256) s[i] = es[i];
  __syncthreads();
  int i = blockIdx.x * 4 + (t >> 6), lane = t & 63;
  float si = s[i];
  int rank = 0;
  for (int j = lane; j < NE; j += 64) {
    float sj = s[j];
    rank += (sj > si) || (sj == si && j < i);
  }
  #pragma unroll
  for (int m = 32; m >= 1; m >>= 1) rank += __shfl_xor(rank, m);
  if (lane == 0)
    edge_mask[i] = ((rank < EDGE_K) && node_mask[src[i]] && node_mask[dst[i]]) ? 1 : 0;
}

// ---------- shared GEMM pass (BT=512): acc[4] += As(16x128 LDS) @ Wg ----------
// thread t: j = t&127 (output col), rg = t>>7 in 0..3 (4 rows each)
__device__ __forceinline__ void gemm_pass(const float* __restrict__ Wg,
                                          float* __restrict__ Wl,
                                          const float* __restrict__ As,
                                          int j, int rg, float acc[4]) {
  for (int half = 0; half < 2; ++half) {
    __syncthreads();
    for (int i = threadIdx.x; i < 64 * D / 4; i += BT)
      ((float4*)Wl)[i] = ((const float4*)Wg)[half * (64 * D / 4) + i];
    __syncthreads();
    #pragma unroll 4
    for (int k4 = 0; k4 < 16; ++k4) {
      int kr = k4 * 4;
      int k0 = half * 64 + kr;
      float w0 = Wl[(kr + 0) * D + j];
      float w1 = Wl[(kr + 1) * D + j];
      float w2 = Wl[(kr + 2) * D + j];
      float w3 = Wl[(kr + 3) * D + j];
      #pragma unroll
      for (int r = 0; r < 4; ++r) {
        float4 a = ((const float4*)As)[((rg * 4 + r) * D + k0) >> 2];
        acc[r] += a.x * w0 + a.y * w1 + a.z * w2 + a.w * w3;
      }
    }
  }
}

// ---------- fused: gather(efm,nsum) -> h -> q,k,v (5 GEMM passes) ----------
__global__ __launch_bounds__(BT) void h_qkv_kernel(
    const void* __restrict__ rawEF, const void* __restrict__ rawNF,
    const int* __restrict__ src, const int* __restrict__ dst,
    const int* __restrict__ edge_mask, const int* __restrict__ flag,
    const float* __restrict__ WE, const float* __restrict__ WN,
    const float* __restrict__ WQ0,  // WQ,WK,WV contiguous
    float* __restrict__ qkv) {
  __shared__ __align__(16) float Wl[64 * D];   // 32 KB
  __shared__ __align__(16) float A1[ROWS * D]; // efm, reused as h
  __shared__ __align__(16) float A2[ROWS * D]; // nsum
  int t = threadIdx.x;
  int row0 = blockIdx.x * ROWS;
  int f = flag[0];
  {
    int i = t;                       // exactly ROWS*D/4 = 512 float4 slots
    int e = row0 + (i >> 5), c4 = i & 31;
    float m = edge_mask[e] ? 1.f : 0.f;
    float4 ef4 = ldx4(rawEF, (size_t)e * 32 + c4, f);
    ((float4*)A1)[i] = make_float4(m * ef4.x, m * ef4.y, m * ef4.z, m * ef4.w);
    float4 s4 = ldx4(rawNF, (size_t)src[e] * 32 + c4, f);
    float4 d4 = ldx4(rawNF, (size_t)dst[e] * 32 + c4, f);
    ((float4*)A2)[i] = make_float4(s4.x + d4.x, s4.y + d4.y, s4.z + d4.z, s4.w + d4.w);
  }
  int j = t & 127, rg = t >> 7;
  float acc[4] = {0, 0, 0, 0};
  gemm_pass(WE, Wl, A1, j, rg, acc);   // h += efm @ w_e
  gemm_pass(WN, Wl, A2, j, rg, acc);   // h += nsum @ w_n
  __syncthreads();
  #pragma unroll
  for (int r = 0; r < 4; ++r) A1[(rg * 4 + r) * D + j] = acc[r];  // A1 := h
  for (int sel = 0; sel < 3; ++sel) {  // q,k,v (leading sync makes h visible)
    float a2[4] = {0, 0, 0, 0};
    gemm_pass(WQ0 + (size_t)sel * D * D, Wl, A1, j, rg, a2);
    float* C = qkv + (size_t)sel * NE * D;
    #pragma unroll
    for (int r = 0; r < 4; ++r) C[(size_t)(row0 + rg * 4 + r) * D + j] = a2[r];
  }
}

// ---------- sparse edge attention: one block (128 thr) per query edge ----------
__global__ void attn_kernel(const float* __restrict__ q, const float* __restrict__ k,
                            const float* __restrict__ v, const int* __restrict__ src,
                            const int* __restrict__ dst, const int* __restrict__ deg,
                            const int* __restrict__ lists, float* __restrict__ ao) {
  int e = blockIdx.x;
  int j = threadIdx.x;  // head = j/32, d = j%32 (shfl_xor<32 stays in-head)
  float qj = q[e * D + j];
  int sn = src[e], dn = dst[e];
  float m = -1e30f, l = 0.f, acc = 0.f;
  const float scale = 0.17677669529663687f;  // 1/sqrt(32)
  int degA = max(0, min(deg[sn], CAP));
  for (int i = 0; i < degA; ++i) {
    int f = lists[sn * CAP + i];
    float p = qj * k[f * D + j];
    p += __shfl_xor(p, 16); p += __shfl_xor(p, 8); p += __shfl_xor(p, 4);
    p += __shfl_xor(p, 2);  p += __shfl_xor(p, 1);
    float s = p * scale;
    float vj = v[f * D + j];
    float mn = fmaxf(m, s);
    float corr = expf(m - mn);
    float w = expf(s - mn);
    l = l * corr + w;
    acc = acc * corr + w * vj;
    m = mn;
  }
  if (dn != sn) {
    int degB = max(0, min(deg[dn], CAP));
    for (int i = 0; i < degB; ++i) {
      int f = lists[dn * CAP + i];
      if (src[f] == sn || dst[f] == sn) continue;  // already in list A
      float p = qj * k[f * D + j];
      p += __shfl_xor(p, 16); p += __shfl_xor(p, 8); p += __shfl_xor(p, 4);
      p += __shfl_xor(p, 2);  p += __shfl_xor(p, 1);
      float s = p * scale;
      float vj = v[f * D + j];
      float mn = fmaxf(m, s);
      float corr = expf(m - mn);
      float w = expf(s - mn);
      l = l * corr + w;
      acc = acc * corr + w * vj;
      m = mn;
    }
  }
  ao[e * D + j] = acc / fmaxf(l, 1e-37f);
}

// ---------- fused epilogue: o = ao@WO; x = gelu(o@W1+b1); logits = x@W2+b2 -------
__global__ __launch_bounds__(BT) void o_mlp_logits_kernel(
    const float* __restrict__ ao, const float* __restrict__ WO,
    const float* __restrict__ W1, const float* __restrict__ B1,
    const float* __restrict__ W2, const float* __restrict__ B2,
    const int* __restrict__ flag, void* __restrict__ out) {
  __shared__ __align__(16) float Wl[64 * D];   // 32 KB
  __shared__ __align__(16) float Al[ROWS * D]; // ao rows, reused as x
  __shared__ __align__(16) float Bl[ROWS * D]; // o rows
  int t = threadIdx.x;
  int row0 = blockIdx.x * ROWS;
  ((float4*)Al)[t] = ((const float4*)ao)[(size_t)blockIdx.x * (ROWS * D / 4) + t];
  int j = t & 127, rg = t >> 7;
  float acc[4] = {0, 0, 0, 0};
  gemm_pass(WO, Wl, Al, j, rg, acc);   // o = ao @ w_o
  __syncthreads();
  #pragma unroll
  for (int r = 0; r < 4; ++r) Bl[(rg * 4 + r) * D + j] = acc[r];
  float acc2[4] = {0, 0, 0, 0};
  gemm_pass(W1, Wl, Bl, j, rg, acc2);  // leading sync makes Bl visible
  float bj = B1[j];
  __syncthreads();                     // all reads of Al done before overwrite
  #pragma unroll
  for (int r = 0; r < 4; ++r) {        // x = gelu(o@w1 + b1)
    float u = acc2[r] + bj;
    float inner = 0.7978845608028654f * (u + 0.044715f * u * u * u);
    Al[(rg * 4 + r) * D + j] = 0.5f * u * (1.f + tanhf(inner));
  }
  __syncthreads();
  for (int i = t; i < D * 16; i += BT) Wl[i] = W2[i];
  __syncthreads();
  if (t < 256) {                       // logits = x @ w2 + b2
    int r = t >> 4, c = t & 15;
    float s = 0.f;
    for (int kk = 0; kk < D; ++kk) s += Al[r * D + kk] * Wl[kk * 16 + c];
    s += B2[c];
    int idx = (row0 + r) * 16 + c;
    if (flag[0]) ((float*)out)[idx] = s;
    else ((__hip_bfloat16*)out)[idx] = __float2bfloat16(s);
  }
}

extern "C" void kernel_launch(void* const* d_in, const int* in_sizes, int n_in,
                              void* d_out, int out_size, void* d_ws, size_t ws_size,
                              hipStream_t stream) {
  const int* eidx = (const int*)d_in[2];
  const int* src = eidx;
  const int* dst = eidx + NE;

  size_t off = 0;
  char* base = (char*)d_ws;
  auto alloc = [&](size_t nbytes) -> void* {
    void* p = base + off;
    off += (nbytes + 255) & ~(size_t)255;
    return p;
  };
  int* flag        = (int*)alloc(256);
  float* F         = (float*)alloc((size_t)TOTAL_W * sizeof(float));
  float* ns        = (float*)alloc(NN * sizeof(float));
  float* es        = (float*)alloc(NE * sizeof(float));
  int* node_mask   = (int*)alloc(NN * sizeof(int));
  int* edge_mask   = (int*)alloc(NE * sizeof(int));
  int* deg         = (int*)alloc(NN * sizeof(int));
  int* lists       = (int*)alloc((size_t)NN * CAP * sizeof(int));
  float* qkv       = (float*)alloc((size_t)3 * NE * D * sizeof(float));
  float* ao        = (float*)alloc((size_t)NE * D * sizeof(float));
  float* qb = qkv, *kb = qkv + NE * D, *vb = qkv + 2 * NE * D;

  const float* WRN = F + 0;
  const float* WRE = F + 128;
  const float* WE  = F + 256;
  const float* WNp = F + 16640;
  const float* WQ  = F + 33024;   // WQ,WK,WV contiguous
  const float* WO  = F + 82176;
  const float* W1  = F + 98560;
  const float* B1  = F + 114944;
  const float* W2P = F + 115072;
  const float* B2P = F + 117120;

  CvtSrc srcs;
  srcs.p[0]  = d_in[3];  srcs.p[1]  = d_in[4];  srcs.p[2]  = d_in[5];
  srcs.p[3]  = d_in[6];  srcs.p[4]  = d_in[7];  srcs.p[5]  = d_in[8];
  srcs.p[6]  = d_in[9];  srcs.p[7]  = d_in[10]; srcs.p[8]  = d_in[11];
  srcs.p[9]  = d_in[12]; srcs.p[10] = d_in[13]; srcs.p[11] = d_in[14];

  convert_kernel<<<64, 256, 0, stream>>>((const unsigned short*)d_in[0], srcs,
                                         F, flag, deg);
  scores_lists_kernel<<<SCORE_BLOCKS + NE / 256, 256, 0, stream>>>(
      d_in[0], d_in[1], WRN, WRE, flag, ns, es, src, dst, deg, lists);
  node_mask_kernel<<<NN / 4, 256, 0, stream>>>(ns, node_mask);
  edge_mask_kernel<<<NE / 4, 256, 0, stream>>>(es, src, dst, node_mask, edge_mask);
  h_qkv_kernel<<<NE / ROWS, BT, 0, stream>>>(d_in[1], d_in[0], src, dst, edge_mask,
                                             flag, WE, WNp, WQ, qkv);
  attn_kernel<<<NE, 128, 0, stream>>>(qb, kb, vb, src, dst, deg, lists, ao);
  o_mlp_logits_kernel<<<NE / ROWS, BT, 0, stream>>>(ao, WO, W1, B1, W2P, B2P,
                                                    flag, d_out);
}